// Round 1
// baseline (3235.127 us; speedup 1.0000x reference)
//
#include <hip/hip_runtime.h>
#include <cstdint>
#include <cstddef>

// Problem constants (match reference)
#define NB 8          // B clouds
#define NP 4096       // N points per cloud
#define NC 64         // C feature channels
#define NM 2048       // M sampled centroids
#define NK 64         // K max neighbors
#define H1 64
#define H2 64
#define NOUT 128
#define CAND_CAP 1024
#define MSG_LD 68     // padded LDS leading dim (17*16B -> float4-aligned rows)

static __device__ __forceinline__ float sq3(float x, float y, float z) {
    // ((x*x + y*y) + z*z) with no FMA contraction, matching numpy order
    return __fadd_rn(__fadd_rn(__fmul_rn(x, x), __fmul_rn(y, y)), __fmul_rn(z, z));
}

// ---------------------------------------------------------------------------
// Kernel 1: exact FPS per cloud (8 blocks x 256 threads).
// Also emits pos_s, batch_s outputs and the float4 (x,y,z,|p|^2) table.
// ---------------------------------------------------------------------------
__global__ __launch_bounds__(256, 1)
void fps_kernel(const float* __restrict__ pos,
                float4* __restrict__ p4,
                float* __restrict__ pos_s,
                float* __restrict__ batch_s)
{
    __shared__ float px[NP], py[NP], pz[NP];
    __shared__ int s_idx[NM];
    __shared__ unsigned long long red[2][4];

    const int b = blockIdx.x;
    const int t = threadIdx.x;
    const float* p = pos + (size_t)b * NP * 3;

    for (int j = t; j < NP; j += 256) {
        float x = p[j * 3 + 0], y = p[j * 3 + 1], z = p[j * 3 + 2];
        px[j] = x; py[j] = y; pz[j] = z;
        p4[b * NP + j] = make_float4(x, y, z, sq3(x, y, z));
    }
    if (t == 0) s_idx[0] = 0;
    __syncthreads();

    float md[16];
#pragma unroll
    for (int i = 0; i < 16; ++i) md[i] = __builtin_inff();

    int last = 0;
    for (int m = 1; m < NM; ++m) {
        const float lx = px[last], ly = py[last], lz = pz[last];
        unsigned long long best = 0ull;
#pragma unroll
        for (int i = 0; i < 16; ++i) {
            int j = t + (i << 8);
            float dx = __fsub_rn(px[j], lx);
            float dy = __fsub_rn(py[j], ly);
            float dz = __fsub_rn(pz[j], lz);
            float d = sq3(dx, dy, dz);
            float v = fminf(md[i], d);
            md[i] = v;
            unsigned long long key =
                ((unsigned long long)__float_as_uint(v) << 32) |
                (unsigned long long)(0xFFFFFFFFu - (unsigned)j);
            best = (key > best) ? key : best;
        }
#pragma unroll
        for (int o = 32; o > 0; o >>= 1) {
            unsigned long long other = __shfl_xor(best, o, 64);
            best = (other > best) ? other : best;
        }
        const int par = m & 1;
        if ((t & 63) == 0) red[par][t >> 6] = best;
        __syncthreads();
        unsigned long long g = red[par][0];
        g = (red[par][1] > g) ? red[par][1] : g;
        g = (red[par][2] > g) ? red[par][2] : g;
        g = (red[par][3] > g) ? red[par][3] : g;
        last = (int)(0xFFFFFFFFu - (unsigned)(g & 0xFFFFFFFFull));
        if (t == 0) s_idx[m] = last;
        // next iteration writes red[1-par]; red[par] is rewritten only after
        // another barrier has passed -> single barrier per iteration is safe
    }
    __syncthreads();

    for (int m = t; m < NM; m += 256) {
        int j = s_idx[m];
        size_t o = (size_t)(b * NM + m);
        pos_s[o * 3 + 0] = px[j];
        pos_s[o * 3 + 1] = py[j];
        pos_s[o * 3 + 2] = pz[j];
        batch_s[o] = (float)b;
    }
}

// ---------------------------------------------------------------------------
// Kernel 2: radius ball query + exact top-K (K nearest within R) per centroid.
// One wave per centroid; 4 waves per block (same cloud).
// ---------------------------------------------------------------------------
__global__ __launch_bounds__(256, 1)
void ball_kernel(const float4* __restrict__ p4,
                 const float* __restrict__ pos_s,
                 int* __restrict__ nbr,
                 int* __restrict__ cnt_out)
{
    __shared__ unsigned long long cand[4][CAND_CAP];
    const float R2 = 0.04f;  // f32(R*R)

    const int wv = threadIdx.x >> 6;
    const int lane = threadIdx.x & 63;
    const int c = blockIdx.x * 4 + wv;         // centroid id in [0, B*M)
    const int b = c >> 11;                     // / NM
    const float4* pc = p4 + b * NP;

    const float sx = pos_s[c * 3 + 0];
    const float sy = pos_s[c * 3 + 1];
    const float sz = pos_s[c * 3 + 2];
    const float ps2 = sq3(sx, sy, sz);

    int n = 0;
    for (int j0 = 0; j0 < NP; j0 += 64) {
        int j = j0 + lane;
        float4 q = pc[j];
        float dot = __fadd_rn(__fadd_rn(__fmul_rn(sx, q.x), __fmul_rn(sy, q.y)),
                              __fmul_rn(sz, q.z));
        float d2 = __fsub_rn(__fadd_rn(ps2, q.w), __fmul_rn(2.0f, dot));
        d2 = fmaxf(d2, 0.0f);
        bool in = (d2 <= R2);
        unsigned long long mask = __ballot(in);
        if (in) {
            int off = __popcll(mask & ((1ull << lane) - 1ull));
            int slot = n + off;
            if (slot < CAND_CAP)
                cand[wv][slot] =
                    ((unsigned long long)__float_as_uint(d2) << 32) |
                    (unsigned long long)(unsigned)j;
        }
        n += __popcll(mask);
    }
    if (n > CAND_CAP) n = CAND_CAP;

    int* nb = nbr + (size_t)c * NK;
    if (n <= NK) {
        for (int i = lane; i < n; i += 64)
            nb[i] = (int)(cand[wv][i] & 0xFFFFFFFFull);
        if (lane == 0) cnt_out[c] = n;
    } else {
        for (int r = 0; r < NK; ++r) {
            unsigned long long lmin = ~0ull;
            int lslot = -1;
            for (int i = lane; i < n; i += 64) {
                unsigned long long v = cand[wv][i];
                if (v < lmin) { lmin = v; lslot = i; }
            }
            unsigned long long gmin = lmin;
#pragma unroll
            for (int o = 32; o > 0; o >>= 1) {
                unsigned long long other = __shfl_xor(gmin, o, 64);
                gmin = (other < gmin) ? other : gmin;
            }
            if (lmin == gmin && lslot >= 0) {   // keys are unique -> one owner
                cand[wv][lslot] = ~0ull;
                nb[r] = (int)(gmin & 0xFFFFFFFFull);
            }
        }
        if (lane == 0) cnt_out[c] = NK;
    }
}

// ---------------------------------------------------------------------------
// Kernel 3: gather messages [x_j, pos_j - pos_i], 3-layer MLP (f32), masked
// max-pool. One block (256 threads) per centroid; everything staged in LDS.
// ---------------------------------------------------------------------------
__global__ __launch_bounds__(256, 1)
void mlp_kernel(const float* __restrict__ x,
                const float4* __restrict__ p4,
                const float* __restrict__ W1, const float* __restrict__ B1,
                const float* __restrict__ W2, const float* __restrict__ B2,
                const float* __restrict__ W3, const float* __restrict__ B3,
                const int* __restrict__ nbr, const int* __restrict__ cnt_arr,
                const float* __restrict__ pos_s,
                float* __restrict__ out)
{
    __shared__ float sW1[67 * 64];
    __shared__ float sW2[64 * 64];
    __shared__ float sW3[64 * 128];
    __shared__ float sB1[64], sB2[64], sB3[128];
    __shared__ float msg[67 * MSG_LD];   // [k][n], k-major
    __shared__ float hA[64 * MSG_LD];
    __shared__ float hB[64 * MSG_LD];
    __shared__ int obuf[128];
    __shared__ int s_nb[64];

    const int t = threadIdx.x;
    const int c = blockIdx.x;
    const int b = c >> 11;
    const int cnt = cnt_arr[c];

    if (t < 128) obuf[t] = 0;
    if (t < 64) s_nb[t] = (t < cnt) ? nbr[(size_t)c * NK + t] : -1;
    for (int i = t; i < 67 * 64; i += 256) sW1[i] = W1[i];
    for (int i = t; i < 64 * 64; i += 256) sW2[i] = W2[i];
    for (int i = t; i < 64 * 128; i += 256) sW3[i] = W3[i];
    if (t < 64) { sB1[t] = B1[t]; sB2[t] = B2[t]; }
    if (t < 128) sB3[t] = B3[t];
    const float sx = pos_s[c * 3 + 0];
    const float sy = pos_s[c * 3 + 1];
    const float sz = pos_s[c * 3 + 2];
    __syncthreads();

    // gather x_j -> msg[0..63][n], rel -> msg[64..66][n]
    {
        int n = t >> 2, q = t & 3;
        int j = s_nb[n];
        const float4* row = (const float4*)(x + ((size_t)b * NP + (j < 0 ? 0 : j)) * NC);
#pragma unroll
        for (int s = 0; s < 4; ++s) {
            int k4 = q * 4 + s;
            float4 v = (j >= 0) ? row[k4] : make_float4(0.f, 0.f, 0.f, 0.f);
            msg[(k4 * 4 + 0) * MSG_LD + n] = v.x;
            msg[(k4 * 4 + 1) * MSG_LD + n] = v.y;
            msg[(k4 * 4 + 2) * MSG_LD + n] = v.z;
            msg[(k4 * 4 + 3) * MSG_LD + n] = v.w;
        }
        if (t < 64) {
            int jj = s_nb[t];
            float rx = 0.f, ry = 0.f, rz = 0.f;
            if (jj >= 0) {
                float4 pj = p4[b * NP + jj];
                rx = __fsub_rn(pj.x, sx);
                ry = __fsub_rn(pj.y, sy);
                rz = __fsub_rn(pj.z, sz);
            }
            msg[64 * MSG_LD + t] = rx;
            msg[65 * MSG_LD + t] = ry;
            msg[66 * MSG_LD + t] = rz;
        }
    }
    __syncthreads();

    const int tn = (t >> 4) << 2;   // n0: 4 neighbors
    const int tf = (t & 15) << 2;   // f0: 4 features

    // ---- layer 1: [64n x 67k] @ [67k x 64f]
    {
        float acc[4][4];
#pragma unroll
        for (int i = 0; i < 4; ++i)
#pragma unroll
            for (int j = 0; j < 4; ++j) acc[i][j] = 0.f;
        for (int k = 0; k < 67; ++k) {
            float4 a = *(const float4*)&msg[k * MSG_LD + tn];
            float4 w = *(const float4*)&sW1[k * 64 + tf];
            float av[4] = {a.x, a.y, a.z, a.w};
            float wv[4] = {w.x, w.y, w.z, w.w};
#pragma unroll
            for (int i = 0; i < 4; ++i)
#pragma unroll
                for (int j = 0; j < 4; ++j)
                    acc[i][j] = fmaf(av[i], wv[j], acc[i][j]);
        }
#pragma unroll
        for (int j = 0; j < 4; ++j) {
            float bias = sB1[tf + j];
#pragma unroll
            for (int i = 0; i < 4; ++i)
                hA[(tf + j) * MSG_LD + (tn + i)] = fmaxf(acc[i][j] + bias, 0.f);
        }
    }
    __syncthreads();

    // ---- layer 2: [64n x 64k] @ [64k x 64f]
    {
        float acc[4][4];
#pragma unroll
        for (int i = 0; i < 4; ++i)
#pragma unroll
            for (int j = 0; j < 4; ++j) acc[i][j] = 0.f;
        for (int k = 0; k < 64; ++k) {
            float4 a = *(const float4*)&hA[k * MSG_LD + tn];
            float4 w = *(const float4*)&sW2[k * 64 + tf];
            float av[4] = {a.x, a.y, a.z, a.w};
            float wv[4] = {w.x, w.y, w.z, w.w};
#pragma unroll
            for (int i = 0; i < 4; ++i)
#pragma unroll
                for (int j = 0; j < 4; ++j)
                    acc[i][j] = fmaf(av[i], wv[j], acc[i][j]);
        }
#pragma unroll
        for (int j = 0; j < 4; ++j) {
            float bias = sB2[tf + j];
#pragma unroll
            for (int i = 0; i < 4; ++i)
                hB[(tf + j) * MSG_LD + (tn + i)] = fmaxf(acc[i][j] + bias, 0.f);
        }
    }
    __syncthreads();

    // ---- layer 3: [64n x 64k] @ [64k x 128f] + masked max-pool
    {
        const int tf3 = (t & 15) << 3;  // 8 features
        float acc[4][8];
#pragma unroll
        for (int i = 0; i < 4; ++i)
#pragma unroll
            for (int j = 0; j < 8; ++j) acc[i][j] = 0.f;
        for (int k = 0; k < 64; ++k) {
            float4 a = *(const float4*)&hB[k * MSG_LD + tn];
            float4 w0 = *(const float4*)&sW3[k * 128 + tf3];
            float4 w1 = *(const float4*)&sW3[k * 128 + tf3 + 4];
            float av[4] = {a.x, a.y, a.z, a.w};
            float wv[8] = {w0.x, w0.y, w0.z, w0.w, w1.x, w1.y, w1.z, w1.w};
#pragma unroll
            for (int i = 0; i < 4; ++i)
#pragma unroll
                for (int j = 0; j < 8; ++j)
                    acc[i][j] = fmaf(av[i], wv[j], acc[i][j]);
        }
#pragma unroll
        for (int j = 0; j < 8; ++j) {
            float bias = sB3[tf3 + j];
            float mx = -1.f;
#pragma unroll
            for (int i = 0; i < 4; ++i) {
                if (tn + i < cnt) {
                    float v = fmaxf(acc[i][j] + bias, 0.f);
                    mx = fmaxf(mx, v);
                }
            }
            if (mx >= 0.f) atomicMax(&obuf[tf3 + j], __float_as_int(mx));
        }
    }
    __syncthreads();
    if (t < 128) out[(size_t)c * NOUT + t] = __int_as_float(obuf[t]);
}

// ---------------------------------------------------------------------------
extern "C" void kernel_launch(void* const* d_in, const int* in_sizes, int n_in,
                              void* d_out, int out_size, void* d_ws, size_t ws_size,
                              hipStream_t stream)
{
    (void)in_sizes; (void)n_in; (void)out_size; (void)ws_size;
    const float* x   = (const float*)d_in[0];
    const float* pos = (const float*)d_in[1];
    // d_in[2] = batch (unused: batch[b][n] == b)
    const float* W1 = (const float*)d_in[3];
    const float* B1 = (const float*)d_in[4];
    const float* W2 = (const float*)d_in[5];
    const float* B2 = (const float*)d_in[6];
    const float* W3 = (const float*)d_in[7];
    const float* B3 = (const float*)d_in[8];

    float* out     = (float*)d_out;                       // [B,M,128]
    float* pos_s   = out + (size_t)NB * NM * NOUT;        // [B,M,3]
    float* batch_s = pos_s + (size_t)NB * NM * 3;         // [B,M]

    // workspace: p4 table (512 KB) | nbr (4 MB) | cnt (64 KB)  ~= 4.6 MB
    float4* p4 = (float4*)d_ws;
    int* nbr = (int*)((char*)d_ws + (512 << 10));
    int* cnt = (int*)((char*)d_ws + (512 << 10) + (4 << 20));

    fps_kernel<<<NB, 256, 0, stream>>>(pos, p4, pos_s, batch_s);
    ball_kernel<<<(NB * NM) / 4, 256, 0, stream>>>(p4, pos_s, nbr, cnt);
    mlp_kernel<<<NB * NM, 256, 0, stream>>>(x, p4, W1, B1, W2, B2, W3, B3,
                                            nbr, cnt, pos_s, out);
}

// Round 2
// 2813.618 us; speedup vs baseline: 1.1498x; 1.1498x over previous
//
#include <hip/hip_runtime.h>
#include <cstdint>
#include <cstddef>

// Problem constants (match reference)
#define NB 8          // B clouds
#define NP 4096       // N points per cloud
#define NC 64         // C feature channels
#define NM 2048       // M sampled centroids
#define NK 64         // K max neighbors
#define H1 64
#define H2 64
#define NOUT 128
#define CAND_CAP 1024
#define MSG_LD 68     // padded LDS leading dim (17*16B -> float4-aligned rows)

static __device__ __forceinline__ float sq3(float x, float y, float z) {
    // ((x*x + y*y) + z*z) with no FMA contraction, matching numpy order
    return __fadd_rn(__fadd_rn(__fmul_rn(x, x), __fmul_rn(y, y)), __fmul_rn(z, z));
}

// ---------------------------------------------------------------------------
// Kernel 1: exact FPS per cloud (8 blocks x 512 threads).
// Per-thread points live in REGISTERS (8 pts/thread); the only LDS access in
// the sequential loop is one uniform float4 broadcast + the 8-way wave-partial
// reduce. Also emits pos_s, batch_s and the float4 (x,y,z,|p|^2) table.
// ---------------------------------------------------------------------------
__global__ __launch_bounds__(512, 1)
void fps_kernel(const float* __restrict__ pos,
                float4* __restrict__ p4,
                float* __restrict__ pos_s,
                float* __restrict__ batch_s)
{
    __shared__ float4 pts[NP];                  // 64 KB
    __shared__ int s_idx[NM];                   // 8 KB
    __shared__ unsigned long long red[2][8];

    const int b = blockIdx.x;
    const int t = threadIdx.x;
    const float* p = pos + (size_t)b * NP * 3;

    for (int j = t; j < NP; j += 512) {
        float x = p[j * 3 + 0], y = p[j * 3 + 1], z = p[j * 3 + 2];
        float4 q = make_float4(x, y, z, sq3(x, y, z));
        pts[j] = q;
        p4[b * NP + j] = q;
    }
    if (t == 0) s_idx[0] = 0;
    __syncthreads();

    // thread t owns points j = t + i*512, i in 0..7 (ascending i == ascending j)
    float rx[8], ry[8], rz[8], md[8];
#pragma unroll
    for (int i = 0; i < 8; ++i) {
        float4 q = pts[t + (i << 9)];
        rx[i] = q.x; ry[i] = q.y; rz[i] = q.z;
        md[i] = __builtin_inff();
    }
    const unsigned invt = 0xFFFFFFFFu - (unsigned)t;

    int last = 0;
    for (int m = 1; m < NM; ++m) {
        const float4 L = pts[last];             // uniform broadcast read
        float bv = -__builtin_inff();
        int bi = 0;
#pragma unroll
        for (int i = 0; i < 8; ++i) {
            float dx = __fsub_rn(rx[i], L.x);
            float dy = __fsub_rn(ry[i], L.y);
            float dz = __fsub_rn(rz[i], L.z);
            float d = sq3(dx, dy, dz);
            float v = fminf(md[i], d);
            md[i] = v;
            if (v > bv) { bv = v; bi = i; }     // strict > keeps smallest j on tie
        }
        // key: larger value wins; on value tie, smaller j wins (argmax semantics)
        unsigned long long best =
            ((unsigned long long)__float_as_uint(bv) << 32) |
            (unsigned long long)(invt - (unsigned)(bi << 9));
#pragma unroll
        for (int o = 32; o > 0; o >>= 1) {
            unsigned long long other = __shfl_xor(best, o, 64);
            best = (other > best) ? other : best;
        }
        const int par = m & 1;
        if ((t & 63) == 0) red[par][t >> 6] = best;
        __syncthreads();
        unsigned long long g = red[par][0];
#pragma unroll
        for (int w = 1; w < 8; ++w) {
            unsigned long long v = red[par][w];
            g = (v > g) ? v : g;
        }
        last = (int)(0xFFFFFFFFu - (unsigned)(g & 0xFFFFFFFFull));
        if (t == 0) s_idx[m] = last;
        // red ping-pongs on parity; one barrier per iteration is race-free
    }
    __syncthreads();

    for (int m = t; m < NM; m += 512) {
        int j = s_idx[m];
        size_t o = (size_t)(b * NM + m);
        float4 q = pts[j];
        pos_s[o * 3 + 0] = q.x;
        pos_s[o * 3 + 1] = q.y;
        pos_s[o * 3 + 2] = q.z;
        batch_s[o] = (float)b;
    }
}

// ---------------------------------------------------------------------------
// Kernel 2: radius ball query + exact top-K (K nearest within R) per centroid.
// One wave per centroid; 4 waves per block (same cloud).
// ---------------------------------------------------------------------------
__global__ __launch_bounds__(256, 1)
void ball_kernel(const float4* __restrict__ p4,
                 const float* __restrict__ pos_s,
                 int* __restrict__ nbr,
                 int* __restrict__ cnt_out)
{
    __shared__ unsigned long long cand[4][CAND_CAP];
    const float R2 = 0.04f;  // f32(R*R)

    const int wv = threadIdx.x >> 6;
    const int lane = threadIdx.x & 63;
    const int c = blockIdx.x * 4 + wv;         // centroid id in [0, B*M)
    const int b = c >> 11;                     // / NM
    const float4* pc = p4 + b * NP;

    const float sx = pos_s[c * 3 + 0];
    const float sy = pos_s[c * 3 + 1];
    const float sz = pos_s[c * 3 + 2];
    const float ps2 = sq3(sx, sy, sz);

    int n = 0;
    for (int j0 = 0; j0 < NP; j0 += 64) {
        int j = j0 + lane;
        float4 q = pc[j];
        float dot = __fadd_rn(__fadd_rn(__fmul_rn(sx, q.x), __fmul_rn(sy, q.y)),
                              __fmul_rn(sz, q.z));
        float d2 = __fsub_rn(__fadd_rn(ps2, q.w), __fmul_rn(2.0f, dot));
        d2 = fmaxf(d2, 0.0f);
        bool in = (d2 <= R2);
        unsigned long long mask = __ballot(in);
        if (in) {
            int off = __popcll(mask & ((1ull << lane) - 1ull));
            int slot = n + off;
            if (slot < CAND_CAP)
                cand[wv][slot] =
                    ((unsigned long long)__float_as_uint(d2) << 32) |
                    (unsigned long long)(unsigned)j;
        }
        n += __popcll(mask);
    }
    if (n > CAND_CAP) n = CAND_CAP;

    int* nb = nbr + (size_t)c * NK;
    if (n <= NK) {
        for (int i = lane; i < n; i += 64)
            nb[i] = (int)(cand[wv][i] & 0xFFFFFFFFull);
        if (lane == 0) cnt_out[c] = n;
    } else {
        for (int r = 0; r < NK; ++r) {
            unsigned long long lmin = ~0ull;
            int lslot = -1;
            for (int i = lane; i < n; i += 64) {
                unsigned long long v = cand[wv][i];
                if (v < lmin) { lmin = v; lslot = i; }
            }
            unsigned long long gmin = lmin;
#pragma unroll
            for (int o = 32; o > 0; o >>= 1) {
                unsigned long long other = __shfl_xor(gmin, o, 64);
                gmin = (other < gmin) ? other : gmin;
            }
            if (lmin == gmin && lslot >= 0) {   // keys are unique -> one owner
                cand[wv][lslot] = ~0ull;
                nb[r] = (int)(gmin & 0xFFFFFFFFull);
            }
        }
        if (lane == 0) cnt_out[c] = NK;
    }
}

// ---------------------------------------------------------------------------
// Kernel 3: gather messages [x_j, pos_j - pos_i], 3-layer MLP (f32), masked
// max-pool. One block (256 threads) per centroid; everything staged in LDS.
// ---------------------------------------------------------------------------
__global__ __launch_bounds__(256, 1)
void mlp_kernel(const float* __restrict__ x,
                const float4* __restrict__ p4,
                const float* __restrict__ W1, const float* __restrict__ B1,
                const float* __restrict__ W2, const float* __restrict__ B2,
                const float* __restrict__ W3, const float* __restrict__ B3,
                const int* __restrict__ nbr, const int* __restrict__ cnt_arr,
                const float* __restrict__ pos_s,
                float* __restrict__ out)
{
    __shared__ float sW1[67 * 64];
    __shared__ float sW2[64 * 64];
    __shared__ float sW3[64 * 128];
    __shared__ float sB1[64], sB2[64], sB3[128];
    __shared__ float msg[67 * MSG_LD];   // [k][n], k-major
    __shared__ float hA[64 * MSG_LD];
    __shared__ float hB[64 * MSG_LD];
    __shared__ int obuf[128];
    __shared__ int s_nb[64];

    const int t = threadIdx.x;
    const int c = blockIdx.x;
    const int b = c >> 11;
    const int cnt = cnt_arr[c];

    if (t < 128) obuf[t] = 0;
    if (t < 64) s_nb[t] = (t < cnt) ? nbr[(size_t)c * NK + t] : -1;
    for (int i = t; i < 67 * 64; i += 256) sW1[i] = W1[i];
    for (int i = t; i < 64 * 64; i += 256) sW2[i] = W2[i];
    for (int i = t; i < 64 * 128; i += 256) sW3[i] = W3[i];
    if (t < 64) { sB1[t] = B1[t]; sB2[t] = B2[t]; }
    if (t < 128) sB3[t] = B3[t];
    const float sx = pos_s[c * 3 + 0];
    const float sy = pos_s[c * 3 + 1];
    const float sz = pos_s[c * 3 + 2];
    __syncthreads();

    // gather x_j -> msg[0..63][n], rel -> msg[64..66][n]
    {
        int n = t >> 2, q = t & 3;
        int j = s_nb[n];
        const float4* row = (const float4*)(x + ((size_t)b * NP + (j < 0 ? 0 : j)) * NC);
#pragma unroll
        for (int s = 0; s < 4; ++s) {
            int k4 = q * 4 + s;
            float4 v = (j >= 0) ? row[k4] : make_float4(0.f, 0.f, 0.f, 0.f);
            msg[(k4 * 4 + 0) * MSG_LD + n] = v.x;
            msg[(k4 * 4 + 1) * MSG_LD + n] = v.y;
            msg[(k4 * 4 + 2) * MSG_LD + n] = v.z;
            msg[(k4 * 4 + 3) * MSG_LD + n] = v.w;
        }
        if (t < 64) {
            int jj = s_nb[t];
            float rx = 0.f, ry = 0.f, rz = 0.f;
            if (jj >= 0) {
                float4 pj = p4[b * NP + jj];
                rx = __fsub_rn(pj.x, sx);
                ry = __fsub_rn(pj.y, sy);
                rz = __fsub_rn(pj.z, sz);
            }
            msg[64 * MSG_LD + t] = rx;
            msg[65 * MSG_LD + t] = ry;
            msg[66 * MSG_LD + t] = rz;
        }
    }
    __syncthreads();

    const int tn = (t >> 4) << 2;   // n0: 4 neighbors
    const int tf = (t & 15) << 2;   // f0: 4 features

    // ---- layer 1: [64n x 67k] @ [67k x 64f]
    {
        float acc[4][4];
#pragma unroll
        for (int i = 0; i < 4; ++i)
#pragma unroll
            for (int j = 0; j < 4; ++j) acc[i][j] = 0.f;
        for (int k = 0; k < 67; ++k) {
            float4 a = *(const float4*)&msg[k * MSG_LD + tn];
            float4 w = *(const float4*)&sW1[k * 64 + tf];
            float av[4] = {a.x, a.y, a.z, a.w};
            float wv[4] = {w.x, w.y, w.z, w.w};
#pragma unroll
            for (int i = 0; i < 4; ++i)
#pragma unroll
                for (int j = 0; j < 4; ++j)
                    acc[i][j] = fmaf(av[i], wv[j], acc[i][j]);
        }
#pragma unroll
        for (int j = 0; j < 4; ++j) {
            float bias = sB1[tf + j];
#pragma unroll
            for (int i = 0; i < 4; ++i)
                hA[(tf + j) * MSG_LD + (tn + i)] = fmaxf(acc[i][j] + bias, 0.f);
        }
    }
    __syncthreads();

    // ---- layer 2: [64n x 64k] @ [64k x 64f]
    {
        float acc[4][4];
#pragma unroll
        for (int i = 0; i < 4; ++i)
#pragma unroll
            for (int j = 0; j < 4; ++j) acc[i][j] = 0.f;
        for (int k = 0; k < 64; ++k) {
            float4 a = *(const float4*)&hA[k * MSG_LD + tn];
            float4 w = *(const float4*)&sW2[k * 64 + tf];
            float av[4] = {a.x, a.y, a.z, a.w};
            float wv[4] = {w.x, w.y, w.z, w.w};
#pragma unroll
            for (int i = 0; i < 4; ++i)
#pragma unroll
                for (int j = 0; j < 4; ++j)
                    acc[i][j] = fmaf(av[i], wv[j], acc[i][j]);
        }
#pragma unroll
        for (int j = 0; j < 4; ++j) {
            float bias = sB2[tf + j];
#pragma unroll
            for (int i = 0; i < 4; ++i)
                hB[(tf + j) * MSG_LD + (tn + i)] = fmaxf(acc[i][j] + bias, 0.f);
        }
    }
    __syncthreads();

    // ---- layer 3: [64n x 64k] @ [64k x 128f] + masked max-pool
    {
        const int tf3 = (t & 15) << 3;  // 8 features
        float acc[4][8];
#pragma unroll
        for (int i = 0; i < 4; ++i)
#pragma unroll
            for (int j = 0; j < 8; ++j) acc[i][j] = 0.f;
        for (int k = 0; k < 64; ++k) {
            float4 a = *(const float4*)&hB[k * MSG_LD + tn];
            float4 w0 = *(const float4*)&sW3[k * 128 + tf3];
            float4 w1 = *(const float4*)&sW3[k * 128 + tf3 + 4];
            float av[4] = {a.x, a.y, a.z, a.w};
            float wv[8] = {w0.x, w0.y, w0.z, w0.w, w1.x, w1.y, w1.z, w1.w};
#pragma unroll
            for (int i = 0; i < 4; ++i)
#pragma unroll
                for (int j = 0; j < 8; ++j)
                    acc[i][j] = fmaf(av[i], wv[j], acc[i][j]);
        }
#pragma unroll
        for (int j = 0; j < 8; ++j) {
            float bias = sB3[tf3 + j];
            float mx = -1.f;
#pragma unroll
            for (int i = 0; i < 4; ++i) {
                if (tn + i < cnt) {
                    float v = fmaxf(acc[i][j] + bias, 0.f);
                    mx = fmaxf(mx, v);
                }
            }
            if (mx >= 0.f) atomicMax(&obuf[tf3 + j], __float_as_int(mx));
        }
    }
    __syncthreads();
    if (t < 128) out[(size_t)c * NOUT + t] = __int_as_float(obuf[t]);
}

// ---------------------------------------------------------------------------
extern "C" void kernel_launch(void* const* d_in, const int* in_sizes, int n_in,
                              void* d_out, int out_size, void* d_ws, size_t ws_size,
                              hipStream_t stream)
{
    (void)in_sizes; (void)n_in; (void)out_size; (void)ws_size;
    const float* x   = (const float*)d_in[0];
    const float* pos = (const float*)d_in[1];
    // d_in[2] = batch (unused: batch[b][n] == b)
    const float* W1 = (const float*)d_in[3];
    const float* B1 = (const float*)d_in[4];
    const float* W2 = (const float*)d_in[5];
    const float* B2 = (const float*)d_in[6];
    const float* W3 = (const float*)d_in[7];
    const float* B3 = (const float*)d_in[8];

    float* out     = (float*)d_out;                       // [B,M,128]
    float* pos_s   = out + (size_t)NB * NM * NOUT;        // [B,M,3]
    float* batch_s = pos_s + (size_t)NB * NM * 3;         // [B,M]

    // workspace: p4 table (512 KB) | nbr (4 MB) | cnt (64 KB)  ~= 4.6 MB
    float4* p4 = (float4*)d_ws;
    int* nbr = (int*)((char*)d_ws + (512 << 10));
    int* cnt = (int*)((char*)d_ws + (512 << 10) + (4 << 20));

    fps_kernel<<<NB, 512, 0, stream>>>(pos, p4, pos_s, batch_s);
    ball_kernel<<<(NB * NM) / 4, 256, 0, stream>>>(p4, pos_s, nbr, cnt);
    mlp_kernel<<<NB * NM, 256, 0, stream>>>(x, p4, W1, B1, W2, B2, W3, B3,
                                            nbr, cnt, pos_s, out);
}